// Round 4
// baseline (56.265 us; speedup 1.0000x reference)
//
#include <hip/hip_runtime.h>

#define BATCH 8192
#define FEAT_DIM 512
#define NUM_CLASSES 2048

#define WAVES_PER_BLOCK 4
#define BLOCKS1 (BATCH / WAVES_PER_BLOCK)    // 2048 blocks, 1 row per wave
#define NGROUPS 64
#define GROUP_SZ (BLOCKS1 / NGROUPS)         // 32 blocks per ticket group
#define CNT_STRIDE 16                        // 16 uints = 64B spacing -> parallel L2 atomics

// Workspace layout (floats):
//   ws[0..2047]                      per-block partial sums
//   cnt = (uint*)(ws + 2048)         NGROUPS L1 counters at cnt[g*16], L2 at cnt[64*16]
// Counters are zeroed each call via hipMemsetAsync (graph-capturable).

__global__ __launch_bounds__(256)
void center_loss_fused(const float* __restrict__ features,
                       const float* __restrict__ centers,
                       const int* __restrict__ target,
                       float* __restrict__ ws,
                       unsigned int* __restrict__ cnt,
                       float* __restrict__ out) {
    const int wave = threadIdx.x >> 6;      // 0..3
    const int lane = threadIdx.x & 63;      // 0..63
    const int row  = blockIdx.x * WAVES_PER_BLOCK + wave;   // 0..8191

    const int t = target[row];
    const float4* __restrict__ fp =
        (const float4*)(features + (size_t)row * FEAT_DIM);
    const float4* __restrict__ cp =
        (const float4*)(centers + (size_t)t * FEAT_DIM);

    // 128 float4 per row; 64 lanes -> 2 float4 from each matrix. All loads first.
    const float4 a0 = fp[lane];
    const float4 a1 = fp[lane + 64];
    const float4 b0 = cp[lane];
    const float4 b1 = cp[lane + 64];

    const float dx0 = a0.x - b0.x, dy0 = a0.y - b0.y;
    const float dz0 = a0.z - b0.z, dw0 = a0.w - b0.w;
    const float dx1 = a1.x - b1.x, dy1 = a1.y - b1.y;
    const float dz1 = a1.z - b1.z, dw1 = a1.w - b1.w;
    float acc = dx0 * dx0 + dy0 * dy0 + dz0 * dz0 + dw0 * dw0
              + dx1 * dx1 + dy1 * dy1 + dz1 * dz1 + dw1 * dw1;

    // 64-lane butterfly reduction (row squared distance).
#pragma unroll
    for (int off = 32; off > 0; off >>= 1)
        acc += __shfl_xor(acc, off, 64);

    __shared__ float s[WAVES_PER_BLOCK];
    __shared__ int winner;
    if (lane == 0)
        s[wave] = fminf(fmaxf(acc, 1e-12f), 1.0e12f);   // per-element clip
    __syncthreads();

    if (threadIdx.x == 0) {
        const float bsum = (s[0] + s[1]) + (s[2] + s[3]);
        ws[blockIdx.x] = bsum;
        __threadfence();   // agent-scope: flush partial to coherence point
        int w = 0;
        // Level 1: 32 blocks per group, 64 spread-out counters (parallel atomics).
        const unsigned old1 =
            atomicAdd(&cnt[(blockIdx.x >> 5) * CNT_STRIDE], 1u);
        if (old1 == GROUP_SZ - 1) {
            // Level 2: 64 group-winners race on one counter (cheap).
            const unsigned old2 = atomicAdd(&cnt[NGROUPS * CNT_STRIDE], 1u);
            w = (old2 == NGROUPS - 1);
        }
        winner = w;
    }
    __syncthreads();

    if (winner) {   // block-uniform branch
        __threadfence();   // acquire side: invalidate stale cached lines
        const int tid = threadIdx.x;
        const float4* __restrict__ wsv = (const float4*)ws;
        const float4 v0 = wsv[tid];
        const float4 v1 = wsv[tid + 256];
        float r = (v0.x + v0.y) + (v0.z + v0.w)
                + (v1.x + v1.y) + (v1.z + v1.w);
#pragma unroll
        for (int off = 32; off > 0; off >>= 1)
            r += __shfl_xor(r, off, 64);

        __shared__ float s2[4];
        if ((tid & 63) == 0) s2[tid >> 6] = r;
        __syncthreads();
        if (tid == 0) {
            out[0] = ((s2[0] + s2[1]) + (s2[2] + s2[3])) * (1.0f / (float)BATCH)
                   + (float)(NUM_CLASSES - 1) * 1e-12f;
        }
    }
}

extern "C" void kernel_launch(void* const* d_in, const int* in_sizes, int n_in,
                              void* d_out, int out_size, void* d_ws, size_t ws_size,
                              hipStream_t stream) {
    const float* features = (const float*)d_in[0];
    const float* centers  = (const float*)d_in[1];
    const int*   target   = (const int*)d_in[2];
    float* out = (float*)d_out;
    float* ws  = (float*)d_ws;
    unsigned int* cnt = (unsigned int*)(ws + BLOCKS1);

    // Zero the ticket counters (NGROUPS spread counters + 1 final), per call.
    hipMemsetAsync(cnt, 0, (NGROUPS * CNT_STRIDE + 1) * sizeof(unsigned int),
                   stream);

    center_loss_fused<<<BLOCKS1, 256, 0, stream>>>(features, centers, target,
                                                   ws, cnt, out);
}

// Round 5
// 9.589 us; speedup vs baseline: 5.8676x; 5.8676x over previous
//
#include <hip/hip_runtime.h>

#define BATCH 8192
#define FEAT_DIM 512
#define NUM_CLASSES 2048

#define WAVES_PER_BLOCK 4
#define NBLOCKS (BATCH / WAVES_PER_BLOCK)   // 2048 blocks, 1 row per wave
#define NGROUPS 64
#define GROUP_SZ (NBLOCKS / NGROUPS)        // 32 blocks per ticket group
#define CNT_STRIDE 16                       // 64B spacing -> parallel atomics

// Workspace layout:
//   float partials[2048]                 — rewritten every call (poison-proof)
//   uint  cnt[g*16], g<64; cnt[64*16]    — NEVER reset; winner test uses
//                                          (old & (N-1)) == N-1, correct for
//                                          any starting value. No memset.
// All cross-block traffic uses device-scope RELAXED atomics (performed at
// the coherence point, no L1/L2 involvement) — NO __threadfence anywhere
// (round-4 lesson: agent release fence = buffer_wbl2 L2 writeback, ~25ns
// x 2048 blocks = +50us).

__global__ __launch_bounds__(256)
void center_loss_fused(const float* __restrict__ features,
                       const float* __restrict__ centers,
                       const int* __restrict__ target,
                       float* __restrict__ partials,
                       unsigned int* __restrict__ cnt,
                       float* __restrict__ out) {
    const int wave = threadIdx.x >> 6;      // 0..3
    const int lane = threadIdx.x & 63;      // 0..63
    const int row  = blockIdx.x * WAVES_PER_BLOCK + wave;   // 0..8191

    const int t = target[row];
    const float4* __restrict__ fp =
        (const float4*)(features + (size_t)row * FEAT_DIM);
    const float4* __restrict__ cp =
        (const float4*)(centers + (size_t)t * FEAT_DIM);

    // 128 float4 per row; 64 lanes -> 2 float4 from each matrix. Loads first.
    const float4 a0 = fp[lane];
    const float4 a1 = fp[lane + 64];
    const float4 b0 = cp[lane];
    const float4 b1 = cp[lane + 64];

    const float dx0 = a0.x - b0.x, dy0 = a0.y - b0.y;
    const float dz0 = a0.z - b0.z, dw0 = a0.w - b0.w;
    const float dx1 = a1.x - b1.x, dy1 = a1.y - b1.y;
    const float dz1 = a1.z - b1.z, dw1 = a1.w - b1.w;
    float acc = dx0 * dx0 + dy0 * dy0 + dz0 * dz0 + dw0 * dw0
              + dx1 * dx1 + dy1 * dy1 + dz1 * dz1 + dw1 * dw1;

    // 64-lane butterfly reduction (row squared distance).
#pragma unroll
    for (int off = 32; off > 0; off >>= 1)
        acc += __shfl_xor(acc, off, 64);

    __shared__ float s[WAVES_PER_BLOCK];
    __shared__ int winner;
    if (lane == 0)
        s[wave] = fminf(fmaxf(acc, 1e-12f), 1.0e12f);   // per-element clip
    __syncthreads();

    if (threadIdx.x == 0) {
        const float bsum = (s[0] + s[1]) + (s[2] + s[3]);
        // Device-coherent single-dword store of this block's partial.
        __hip_atomic_store(&partials[blockIdx.x], bsum,
                           __ATOMIC_RELAXED, __HIP_MEMORY_SCOPE_AGENT);
        // Release-by-completion: the store must be globally performed
        // before the ticket atomic is issued. One waitcnt, no cache flush.
        asm volatile("s_waitcnt vmcnt(0)" ::: "memory");

        const int g = blockIdx.x >> 5;   // 64 groups x 32 blocks
        const unsigned old1 = __hip_atomic_fetch_add(
            &cnt[g * CNT_STRIDE], 1u,
            __ATOMIC_RELAXED, __HIP_MEMORY_SCOPE_AGENT);
        int w = 0;
        if ((old1 & (GROUP_SZ - 1)) == GROUP_SZ - 1) {
            const unsigned old2 = __hip_atomic_fetch_add(
                &cnt[NGROUPS * CNT_STRIDE], 1u,
                __ATOMIC_RELAXED, __HIP_MEMORY_SCOPE_AGENT);
            w = ((old2 & (NGROUPS - 1)) == NGROUPS - 1);
        }
        winner = w;
    }
    __syncthreads();

    if (winner) {   // block-uniform branch; last block to finish reduces
        const int tid = threadIdx.x;
        float r = 0.0f;
#pragma unroll
        for (int i = 0; i < 8; ++i) {
            // L1-bypassing coherent loads; fixed order -> deterministic sum.
            r += __hip_atomic_load(&partials[tid + 256 * i],
                                   __ATOMIC_RELAXED, __HIP_MEMORY_SCOPE_AGENT);
        }
#pragma unroll
        for (int off = 32; off > 0; off >>= 1)
            r += __shfl_xor(r, off, 64);

        __shared__ float s2[4];
        if ((tid & 63) == 0) s2[tid >> 6] = r;
        __syncthreads();
        if (tid == 0) {
            out[0] = ((s2[0] + s2[1]) + (s2[2] + s2[3])) * (1.0f / (float)BATCH)
                   + (float)(NUM_CLASSES - 1) * 1e-12f;
        }
    }
}

extern "C" void kernel_launch(void* const* d_in, const int* in_sizes, int n_in,
                              void* d_out, int out_size, void* d_ws, size_t ws_size,
                              hipStream_t stream) {
    const float* features = (const float*)d_in[0];
    const float* centers  = (const float*)d_in[1];
    const int*   target   = (const int*)d_in[2];
    float* out = (float*)d_out;
    float* partials = (float*)d_ws;
    unsigned int* cnt = (unsigned int*)(partials + NBLOCKS);

    center_loss_fused<<<NBLOCKS, 256, 0, stream>>>(features, centers, target,
                                                   partials, cnt, out);
}

// Round 6
// 9.541 us; speedup vs baseline: 5.8974x; 1.0051x over previous
//
#include <hip/hip_runtime.h>

#define BATCH 8192
#define FEAT_DIM 512
#define NUM_CLASSES 2048

#define WAVES_PER_BLOCK 4
#define NBLOCKS (BATCH / WAVES_PER_BLOCK)   // 2048 blocks = full co-residency (256 CU x 8)
#define NGROUPS 64
#define GROUP_SZ (NBLOCKS / NGROUPS)        // 32 blocks per ticket group
#define CNT_STRIDE 16                       // 64B spacing -> parallel coherence-point RMWs

// Sync design (round-5 post-mortem): EVERY cross-block datum moves via an
// atomic RMW, which executes at the device coherence point (same path as the
// ticket counters, which are proven to work). No plain stores to shared
// buffers, no atomic-store cache-bit assumptions, no fences (round-4 lesson:
// per-block release fences = L2 writebacks = +50us).
//   producer: atomicExch(partial bits) -> s_waitcnt vmcnt(0) -> ticket add
//   winner:   fetch_or(ptr, 0) pure-read RMWs, fixed order -> bit-exact sum
// Counters are never reset; (old & (N-1)) == N-1 selects exactly one winner
// per call regardless of the starting value (incl. 0xAA poison).

__global__ __launch_bounds__(256)
void center_loss_fused(const float* __restrict__ features,
                       const float* __restrict__ centers,
                       const int* __restrict__ target,
                       unsigned int* __restrict__ partials,   // float bits
                       unsigned int* __restrict__ cnt,
                       float* __restrict__ out) {
    const int wave = threadIdx.x >> 6;      // 0..3
    const int lane = threadIdx.x & 63;      // 0..63
    const int row  = blockIdx.x * WAVES_PER_BLOCK + wave;   // 0..8191

    const int t = target[row];
    const float4* __restrict__ fp =
        (const float4*)(features + (size_t)row * FEAT_DIM);
    const float4* __restrict__ cp =
        (const float4*)(centers + (size_t)t * FEAT_DIM);

    // 128 float4 per row; 64 lanes -> 2 float4 from each matrix. Loads first.
    const float4 a0 = fp[lane];
    const float4 a1 = fp[lane + 64];
    const float4 b0 = cp[lane];
    const float4 b1 = cp[lane + 64];

    const float dx0 = a0.x - b0.x, dy0 = a0.y - b0.y;
    const float dz0 = a0.z - b0.z, dw0 = a0.w - b0.w;
    const float dx1 = a1.x - b1.x, dy1 = a1.y - b1.y;
    const float dz1 = a1.z - b1.z, dw1 = a1.w - b1.w;
    float acc = dx0 * dx0 + dy0 * dy0 + dz0 * dz0 + dw0 * dw0
              + dx1 * dx1 + dy1 * dy1 + dz1 * dz1 + dw1 * dw1;

    // 64-lane butterfly reduction (row squared distance).
#pragma unroll
    for (int off = 32; off > 0; off >>= 1)
        acc += __shfl_xor(acc, off, 64);

    __shared__ float s[WAVES_PER_BLOCK];
    __shared__ int winner;
    if (lane == 0)
        s[wave] = fminf(fmaxf(acc, 1e-12f), 1.0e12f);   // per-element clip
    __syncthreads();

    if (threadIdx.x == 0) {
        const float bsum = (s[0] + s[1]) + (s[2] + s[3]);

        // Deliver partial as an RMW at the coherence point.
        (void)__hip_atomic_exchange(&partials[blockIdx.x],
                                    __float_as_uint(bsum),
                                    __ATOMIC_RELAXED, __HIP_MEMORY_SCOPE_AGENT);
        // Completion-before-issue: exch is performed at the coherence point
        // before the ticket RMW is issued. One wait, no cache flush.
        asm volatile("s_waitcnt vmcnt(0)" ::: "memory");

        const unsigned old1 = __hip_atomic_fetch_add(
            &cnt[(blockIdx.x >> 5) * CNT_STRIDE], 1u,
            __ATOMIC_RELAXED, __HIP_MEMORY_SCOPE_AGENT);
        int w = 0;
        if ((old1 & (GROUP_SZ - 1)) == GROUP_SZ - 1) {
            const unsigned old2 = __hip_atomic_fetch_add(
                &cnt[NGROUPS * CNT_STRIDE], 1u,
                __ATOMIC_RELAXED, __HIP_MEMORY_SCOPE_AGENT);
            w = ((old2 & (NGROUPS - 1)) == NGROUPS - 1);
        }
        winner = w;
    }
    __syncthreads();

    if (winner) {   // last block to finish: reduce all partials
        const int tid = threadIdx.x;
        float r = 0.0f;
#pragma unroll
        for (int i = 0; i < 8; ++i) {
            // Pure-read RMW at the coherence point: no cache staleness
            // possible. Fixed order -> bit-deterministic sum.
            const unsigned bits = __hip_atomic_fetch_or(
                &partials[tid + 256 * i], 0u,
                __ATOMIC_RELAXED, __HIP_MEMORY_SCOPE_AGENT);
            r += __uint_as_float(bits);
        }
#pragma unroll
        for (int off = 32; off > 0; off >>= 1)
            r += __shfl_xor(r, off, 64);

        __shared__ float s2[4];
        if ((tid & 63) == 0) s2[tid >> 6] = r;
        __syncthreads();
        if (tid == 0) {
            out[0] = ((s2[0] + s2[1]) + (s2[2] + s2[3])) * (1.0f / (float)BATCH)
                   + (float)(NUM_CLASSES - 1) * 1e-12f;
        }
    }
}

extern "C" void kernel_launch(void* const* d_in, const int* in_sizes, int n_in,
                              void* d_out, int out_size, void* d_ws, size_t ws_size,
                              hipStream_t stream) {
    const float* features = (const float*)d_in[0];
    const float* centers  = (const float*)d_in[1];
    const int*   target   = (const int*)d_in[2];
    float* out = (float*)d_out;
    unsigned int* partials = (unsigned int*)d_ws;
    unsigned int* cnt = partials + NBLOCKS;

    center_loss_fused<<<NBLOCKS, 256, 0, stream>>>(features, centers, target,
                                                   partials, cnt, out);
}